// Round 7
// baseline (23846.153 us; speedup 1.0000x reference)
//
#include <hip/hip_runtime.h>
#include <stdint.h>

// ---------------------------------------------------------------------------
// RPN (Faster R-CNN) for MI355X — BRUTE-FORCE-LITERAL round.
// Every compute stage is one-thread-per-output textbook code straight from the
// raw input tensors (no repacks, no LDS tiling, no fp64): eliminates the last
// uneliminated hypothesis (sparse corruption in the tiled k_head/k_conv that
// 256-point spot checks could miss and that reproduced bit-identically because
// the smem structure was shared across rounds). fp32 throughout, reference op
// order. Top-6000 bitonic sort + literal NMS kept (exonerated: two independent
// implementations agreed bit-identically).
// ---------------------------------------------------------------------------

#define NPOS        9216        // 96*96
#define NCAND       138240      // NPOS*15
#define NPAD        262144      // 2^18 bitonic size
#define PRE_NMS_K   6000
#define POST_NMS_K  300
#define OUT_ROIS    9437184     // rois offset in d_out (floats)
#define LG_OFF      4718592     // logits offset in d_out (floats)

// Anchors (base=16, ratios {0.5,1,2}, scales {2,4,8,16,32}, ratio-major),
// hand-verified 3x against reference _generate_anchors (banker's rounding).
__device__ __constant__ float c_anchors[15][4] = {
  {-15.f,  -4.f,  30.f,  19.f}, {-38.f, -16.f,  53.f,  31.f},
  {-84.f, -40.f,  99.f,  55.f}, {-176.f,-88.f, 191.f, 103.f},
  {-360.f,-184.f,375.f, 199.f},
  { -8.f,  -8.f,  23.f,  23.f}, {-24.f, -24.f,  39.f,  39.f},
  {-56.f, -56.f,  71.f,  71.f}, {-120.f,-120.f,135.f, 135.f},
  {-248.f,-248.f,263.f, 263.f},
  { -3.f, -14.f,  18.f,  29.f}, {-14.f, -36.f,  29.f,  51.f},
  {-36.f, -80.f,  51.f,  95.f}, {-80.f,-168.f,  95.f, 183.f},
  {-168.f,-344.f,183.f, 359.f}};

// ------------------ literal conv3x3 + bias + BN + ReLU ----------------------
// thread = (co, gp); x NCHW [1024][9216]; w OIHW [512][1024][3][3].
__global__ __launch_bounds__(256) void k_conv_lit(
    const float* __restrict__ x, const float* __restrict__ w,
    const float* __restrict__ cb, const float* __restrict__ g,
    const float* __restrict__ be, const float* __restrict__ mn,
    const float* __restrict__ vr, float* __restrict__ xbuf) {
  const int idx = blockIdx.x * 256 + threadIdx.x;   // 4,718,592 threads
  const int co = idx / 9216;
  const int gp = idx - co * 9216;
  const int h = gp / 96, ww = gp - h * 96;
  float acc = 0.f;
  const float* wbase = w + (size_t)co * 9216;       // co*1024*9
  for (int ci = 0; ci < 1024; ++ci) {
    const float* xr = x + (size_t)ci * 9216;
    const float* wr = wbase + ci * 9;
#pragma unroll
    for (int ky = 0; ky < 3; ++ky) {
      const int hy = h + ky - 1;
      if ((unsigned)hy >= 96u) continue;
#pragma unroll
      for (int kx = 0; kx < 3; ++kx) {
        const int wx = ww + kx - 1;
        if ((unsigned)wx >= 96u) continue;
        acc = fmaf(xr[hy * 96 + wx], wr[ky * 3 + kx], acc);
      }
    }
  }
  const float s = g[co] / sqrtf(vr[co] + 1e-5f);
  const float y = ((acc + cb[co]) - mn[co]) * s + be[co];
  xbuf[idx] = fmaxf(y, 0.f);
}

// ------------------------ literal 1x1 heads ---------------------------------
// thread = (c, gp), c in [0,90): c<30 -> score channel, else bbox channel c-30.
__global__ __launch_bounds__(256) void k_head_lit(
    const float* __restrict__ xbuf, const float* __restrict__ sw,
    const float* __restrict__ sb, const float* __restrict__ bw,
    const float* __restrict__ bb, float* __restrict__ lg) {
  const int idx = blockIdx.x * 256 + threadIdx.x;   // 90*9216 = 829,440 exact
  const int c = idx / 9216;
  const int gp = idx - c * 9216;
  const float* wp = (c < 30) ? (sw + (size_t)c * 512)
                             : (bw + (size_t)(c - 30) * 512);
  float acc = 0.f;
  for (int ci = 0; ci < 512; ++ci)
    acc = fmaf(xbuf[(size_t)ci * 9216 + gp], wp[ci], acc);
  lg[idx] = acc + ((c < 30) ? sb[c] : bb[c - 30]);
}

// ---------------- literal softmax + decode + clip + min-size ----------------
// thread = candidate idx = gp*15 + a (matches reference flatten order).
__global__ __launch_bounds__(256) void k_decode_lit(
    const float* __restrict__ lg, const float* __restrict__ iminfo,
    float* __restrict__ scr, float* __restrict__ bx1, float* __restrict__ by1,
    float* __restrict__ bx2, float* __restrict__ by2) {
  const int idx = blockIdx.x * 256 + threadIdx.x;   // 540*256 = 138,240 exact
  const int gp = idx / 15;
  const int a = idx - gp * 15;
  const int h = gp / 96, w = gp - h * 96;
  const float sx = 16.f * (float)w, sy = 16.f * (float)h;
  const float imh = iminfo[0], imw = iminfo[1];
  const float ms = 16.0f * iminfo[2];
  // softmax over the (a, 15+a) channel pair (stable, like jax.nn.softmax)
  const float bg = lg[(size_t)a * 9216 + gp];
  const float fg = lg[(size_t)(15 + a) * 9216 + gp];
  const float m = fmaxf(bg, fg);
  const float eb = expf(bg - m), ef = expf(fg - m);
  const float prob = ef / (eb + ef);
  // deltas: bbox channels 4a..4a+3
  const float d0 = lg[(size_t)(30 + 4 * a + 0) * 9216 + gp];
  const float d1 = lg[(size_t)(30 + 4 * a + 1) * 9216 + gp];
  const float d2 = lg[(size_t)(30 + 4 * a + 2) * 9216 + gp];
  const float d3 = lg[(size_t)(30 + 4 * a + 3) * 9216 + gp];
  const float ax1 = c_anchors[a][0] + sx, ay1 = c_anchors[a][1] + sy;
  const float ax2 = c_anchors[a][2] + sx, ay2 = c_anchors[a][3] + sy;
  const float aw = ax2 - ax1 + 1.0f, ah = ay2 - ay1 + 1.0f;
  const float acx = ax1 + 0.5f * aw, acy = ay1 + 0.5f * ah;
  const float px = d0 * aw + acx, py = d1 * ah + acy;
  const float pw = expf(d2) * aw, ph = expf(d3) * ah;
  const float X1 = fminf(fmaxf(px - 0.5f * pw, 0.f), imw - 1.f);
  const float Y1 = fminf(fmaxf(py - 0.5f * ph, 0.f), imh - 1.f);
  const float X2 = fminf(fmaxf(px + 0.5f * pw - 1.f, 0.f), imw - 1.f);
  const float Y2 = fminf(fmaxf(py + 0.5f * ph - 1.f, 0.f), imh - 1.f);
  const bool keep = ((X2 - X1 + 1.f) >= ms) && ((Y2 - Y1 + 1.f) >= ms);
  scr[idx] = keep ? prob : -1.0f;
  bx1[idx] = X1; by1[idx] = Y1; bx2[idx] = X2; by2[idx] = Y2;
}

// --------------------- key build: score desc, index asc ---------------------
__device__ __forceinline__ unsigned score_key(float s) {
  unsigned b = __float_as_uint(s);
  unsigned asc = b ^ ((b & 0x80000000u) ? 0xFFFFFFFFu : 0x80000000u);
  return ~asc;  // smaller key == larger score (strictly monotonic, injective)
}

__global__ void k_pad(const float* __restrict__ scr,
                      unsigned long long* __restrict__ keys) {
  const int i = blockIdx.x * 256 + threadIdx.x;   // 1024 blocks
  if (i < NPAD) {
    keys[i] = (i < NCAND)
        ? ((((unsigned long long)score_key(scr[i])) << 32) | (unsigned)i)
        : 0xFFFFFFFFFFFFFFFFULL;
  }
}

// --------------------------- bitonic sort (ascending) -----------------------
__global__ void k_sortg(unsigned long long* __restrict__ keys, int j, int k) {
  const int i = blockIdx.x * 256 + threadIdx.x;
  const int l = i ^ j;
  if (l > i) {
    const unsigned long long a = keys[i], b = keys[l];
    const bool up = ((i & k) == 0);
    if ((a > b) == up) { keys[i] = b; keys[l] = a; }
  }
}

__global__ __launch_bounds__(256) void k_sortlds(
    unsigned long long* __restrict__ keys, int k, int jstart) {
  __shared__ unsigned long long tile[4096];
  const int base = blockIdx.x * 4096;             // 64 blocks
  const int t = threadIdx.x;
  for (int e = t; e < 4096; e += 256) tile[e] = keys[base + e];
  __syncthreads();
  for (int j = jstart; j > 0; j >>= 1) {
    for (int p = t; p < 2048; p += 256) {
      const int i = ((p & ~(j - 1)) << 1) | (p & (j - 1));
      const int l = i | j;
      const bool up = (((base + i) & k) == 0);
      const unsigned long long a = tile[i], b = tile[l];
      if ((a > b) == up) { tile[i] = b; tile[l] = a; }
    }
    __syncthreads();
  }
  for (int e = t; e < 4096; e += 256) keys[base + e] = tile[e];
}

// --------------------------- gather sorted top-6000 -------------------------
__global__ void k_gather(const unsigned long long* __restrict__ keys,
                         const float* __restrict__ scr,
                         const float* __restrict__ bx1, const float* __restrict__ by1,
                         const float* __restrict__ bx2, const float* __restrict__ by2,
                         float* __restrict__ ss, float* __restrict__ sx1,
                         float* __restrict__ sy1, float* __restrict__ sx2,
                         float* __restrict__ sy2) {
  const int r = blockIdx.x * 256 + threadIdx.x;   // 24 blocks
  if (r < PRE_NMS_K) {
    const int idx = (int)(keys[r] & 0xFFFFFFFFULL);
    ss[r] = scr[idx];
    sx1[r] = bx1[idx]; sy1[r] = by1[idx];
    sx2[r] = bx2[idx]; sy2[r] = by2[idx];
  }
}

// --------------------- literal NMS (300 fixed iterations) -------------------
__global__ __launch_bounds__(256) void k_nms2(
    const float* __restrict__ ss, const float* __restrict__ sx1,
    const float* __restrict__ sy1, const float* __restrict__ sx2,
    const float* __restrict__ sy2, float* __restrict__ out) {
  __shared__ float rv[256];
  __shared__ int ri[256];
  __shared__ unsigned char alive[PRE_NMS_K];
  __shared__ float jb[4];
  const int t = threadIdx.x;
  for (int j = t; j < PRE_NMS_K; j += 256) alive[j] = (ss[j] >= 0.f) ? 1 : 0;
  __syncthreads();
  for (int it = 0; it < POST_NMS_K; ++it) {
    // argmax over where(alive, ss, -1), first-index tie-break (== jnp.argmax)
    float bv = -2.f; int bi = 0x7FFFFFFF;
    for (int j = t; j < PRE_NMS_K; j += 256) {
      const float v = alive[j] ? ss[j] : -1.f;
      if (v > bv) { bv = v; bi = j; }
    }
    rv[t] = bv; ri[t] = bi;
    __syncthreads();
    for (int o = 128; o > 0; o >>= 1) {
      if (t < o) {
        if (rv[t + o] > rv[t] || (rv[t + o] == rv[t] && ri[t + o] < ri[t])) {
          rv[t] = rv[t + o]; ri[t] = ri[t + o];
        }
      }
      __syncthreads();
    }
    const int j = ri[0];
    const bool ok = rv[0] >= 0.f;
    if (t == 0) {
      out[OUT_ROIS + it * 5 + 0] = 0.f;
      out[OUT_ROIS + it * 5 + 1] = ok ? sx1[j] : 0.f;
      out[OUT_ROIS + it * 5 + 2] = ok ? sy1[j] : 0.f;
      out[OUT_ROIS + it * 5 + 3] = ok ? sx2[j] : 0.f;
      out[OUT_ROIS + it * 5 + 4] = ok ? sy2[j] : 0.f;
      jb[0] = sx1[j]; jb[1] = sy1[j]; jb[2] = sx2[j]; jb[3] = sy2[j];
    }
    __syncthreads();
    const float ax1 = jb[0], ay1 = jb[1], ax2 = jb[2], ay2 = jb[3];
    const float aarea = (ax2 - ax1 + 1.f) * (ay2 - ay1 + 1.f);
    for (int q = t; q < PRE_NMS_K; q += 256) {
      const float xx1 = fmaxf(ax1, sx1[q]);
      const float yy1 = fmaxf(ay1, sy1[q]);
      const float xx2 = fminf(ax2, sx2[q]);
      const float yy2 = fminf(ay2, sy2[q]);
      const float iw = fmaxf(0.f, xx2 - xx1 + 1.f);
      const float ih = fmaxf(0.f, yy2 - yy1 + 1.f);
      const float inter = iw * ih;
      const float barea = (sx2[q] - sx1[q] + 1.f) * (sy2[q] - sy1[q] + 1.f);
      const float iou = inter / (aarea + barea - inter);
      if (!(iou <= 0.7f)) alive[q] = 0;   // literal: valid &= (iou <= 0.7)
    }
    __syncthreads();
  }
}

// ---------------------------------------------------------------------------
extern "C" void kernel_launch(void* const* d_in, const int* in_sizes, int n_in,
                              void* d_out, int out_size, void* d_ws, size_t ws_size,
                              hipStream_t stream) {
  (void)in_sizes; (void)n_in; (void)out_size; (void)ws_size;
  const float* features = (const float*)d_in[0];
  const float* im_info  = (const float*)d_in[1];
  const float* conv1_w  = (const float*)d_in[2];
  const float* conv1_b  = (const float*)d_in[3];
  const float* bn_g     = (const float*)d_in[4];
  const float* bn_b     = (const float*)d_in[5];
  const float* bn_m     = (const float*)d_in[6];
  const float* bn_v     = (const float*)d_in[7];
  const float* score_w  = (const float*)d_in[8];
  const float* score_b  = (const float*)d_in[9];
  const float* bbox_w   = (const float*)d_in[10];
  const float* bbox_b   = (const float*)d_in[11];
  float* out = (float*)d_out;

  // Scratch inside d_out's features region (overwritten by passthrough later):
  float* xbuf = out;                        // [0, 4718592)   conv output
  float* lg   = out + LG_OFF;               // [4718592, 5548032)  90ch logits

  // d_ws: ~5 MB at lowest offsets (verified safe by round-6 host checks).
  float* ws = (float*)d_ws;
  unsigned long long* keys = (unsigned long long*)ws;   // 524,288 f
  float* scr  = ws + 524288;                // 138,240 f each
  float* bx1  = ws + 662528;
  float* by1  = ws + 800768;
  float* bx2  = ws + 939008;
  float* by2  = ws + 1077248;
  float* ss   = ws + 1215488;               // 6,016-strided
  float* sx1  = ws + 1221504;
  float* sy1  = ws + 1227520;
  float* sx2  = ws + 1233536;
  float* sy2  = ws + 1239552;               // end 1,245,568 f

  k_conv_lit<<<18432, 256, 0, stream>>>(features, conv1_w, conv1_b, bn_g,
                                        bn_b, bn_m, bn_v, xbuf);
  k_head_lit<<<3240, 256, 0, stream>>>(xbuf, score_w, score_b, bbox_w,
                                       bbox_b, lg);
  k_decode_lit<<<540, 256, 0, stream>>>(lg, im_info,
                                        scr, bx1, by1, bx2, by2);

  // features passthrough (overwrites xbuf+lg; stream-ordered after decode)
  hipMemcpyAsync(out, features, (size_t)9437184 * sizeof(float),
                 hipMemcpyDeviceToDevice, stream);

  k_pad<<<1024, 256, 0, stream>>>(scr, keys);
  for (int k = 2; k <= NPAD; k <<= 1) {
    int j = k >> 1;
    while (j > 2048) {
      k_sortg<<<1024, 256, 0, stream>>>(keys, j, k);
      j >>= 1;
    }
    k_sortlds<<<64, 256, 0, stream>>>(keys, k, j);
  }
  k_gather<<<24, 256, 0, stream>>>(keys, scr, bx1, by1, bx2, by2,
                                   ss, sx1, sy1, sx2, sy2);
  k_nms2<<<1, 256, 0, stream>>>(ss, sx1, sy1, sx2, sy2, out);
}